// Round 8
// baseline (428.263 us; speedup 1.0000x reference)
//
#include <hip/hip_runtime.h>
#include <cstdint>
#include <cstddef>

typedef __bf16 bf16_t;
typedef __bf16 bf16x8 __attribute__((ext_vector_type(8)));
typedef float  f32x4  __attribute__((ext_vector_type(4)));

#define SEQ 2048
#define NH  16
#define HD  128
#define MM  4096   // b*s rows
#define KK  2048

// async global->LDS, 16B per lane, LDS dest = wave-uniform base + lane*16
#define ASYNC16(g, l) __builtin_amdgcn_global_load_lds( \
    (const __attribute__((address_space(1))) void*)(g), \
    (__attribute__((address_space(3))) void*)(l), 16, 0, 0)

#define MFMA16(a, b, c) __builtin_amdgcn_mfma_f32_16x16x32_bf16((a), (b), (c), 0, 0, 0)

// ---------------------------------------------------------------- one cast kernel
__global__ __launch_bounds__(256) void cast_all(const float* __restrict__ x,
                                                const float* __restrict__ Wq,
                                                const float* __restrict__ Wk,
                                                const float* __restrict__ Wv,
                                                const float* __restrict__ Wo,
                                                bf16_t* __restrict__ xb,
                                                bf16_t* __restrict__ wqkv,
                                                bf16_t* __restrict__ wob) {
    int i = blockIdx.x * 256 + threadIdx.x;     // 0..6M-1 float4 groups
    const float* src;
    bf16_t* dst;
    int off;
    if (i < 2097152) { src = x; dst = xb; off = i; }
    else {
        int j = i - 2097152;
        int sel = j >> 20; off = j & 0xFFFFF;
        if (sel < 3) { src = (sel == 0) ? Wq : (sel == 1) ? Wk : Wv; dst = wqkv + (size_t)sel * 4194304; }
        else         { src = Wo; dst = wob; }
    }
    float4 v = ((const float4*)src)[off];
    union { bf16_t h[4]; uint2 u; } t;
    t.h[0] = (bf16_t)v.x; t.h[1] = (bf16_t)v.y;
    t.h[2] = (bf16_t)v.z; t.h[3] = (bf16_t)v.w;
    ((uint2*)dst)[off] = t.u;
}

// ================================================================ 256x256 QKV GEMM, 4-phase/K-tile
// (R7 harness-verified body; only the Q pre-scale constant changed: now includes
//  log2e so attention's softmax runs on exp2 directly.)
union SMemQ8 {
    bf16_t st[2][32768];     // 128 KB: [buf][ A: frag(mi,ks)*512 | B at +16384 ]
    bf16_t epi[64 * 264];    // epilogue transpose
};

__global__ __launch_bounds__(512, 2) void gemm_qkv(const bf16_t* __restrict__ A,
                                                   const bf16_t* __restrict__ B,
                                                   bf16_t* __restrict__ Qout,
                                                   bf16_t* __restrict__ Kout,
                                                   bf16_t* __restrict__ Vout,
                                                   const int* __restrict__ pos) {
    __shared__ SMemQ8 sm;
    const int tid = threadIdx.x;
    const int w = tid >> 6, l = tid & 63;       // 8 waves
    const int lane16 = l & 15, quad = l >> 4;
    const int tm = blockIdx.y, tn = blockIdx.x; // 256-row / 256-col tiles
    const int wm = w >> 2, wn = w & 3;          // 2M x 4N wave grid

    const int miA0 = wm * 8 + wn;
    const int miA1 = miA0 + 4;
    const int niB0 = (w >> 1) * 4 + (w & 1);
    const int niB1 = niB0 + 2;

    const bf16_t* gA0 = A + (size_t)(tm * 256 + miA0 * 16 + lane16) * KK + quad * 8;
    const bf16_t* gA1 = A + (size_t)(tm * 256 + miA1 * 16 + lane16) * KK + quad * 8;
    const bf16_t* gB0 = B + (size_t)(tn * 256 + niB0 * 16 + lane16) * KK + quad * 8;
    const bf16_t* gB1 = B + (size_t)(tn * 256 + niB1 * 16 + lane16) * KK + quad * 8;

    const int dA0 = miA0 * 1024;
    const int dA1 = miA1 * 1024;
    const int dB0 = 16384 + niB0 * 1024;
    const int dB1 = 16384 + niB1 * 1024;

    f32x4 acc[8][4];
    #pragma unroll
    for (int i = 0; i < 8; i++)
        #pragma unroll
        for (int j = 0; j < 4; j++) acc[i][j] = (f32x4){0.f, 0.f, 0.f, 0.f};

    ASYNC16(gA0,      &sm.st[0][dA0]);
    ASYNC16(gA0 + 32, &sm.st[0][dA0 + 512]);
    ASYNC16(gB0,      &sm.st[0][dB0]);
    ASYNC16(gB0 + 32, &sm.st[0][dB0 + 512]);
    ASYNC16(gB1,      &sm.st[0][dB1]);
    ASYNC16(gB1 + 32, &sm.st[0][dB1 + 512]);
    ASYNC16(gA1,      &sm.st[0][dA1]);
    ASYNC16(gA1 + 32, &sm.st[0][dA1 + 512]);
    gA0 += 64; gA1 += 64; gB0 += 64; gB1 += 64;

    const int NT = KK / 64;                     // 32 K-tiles
    for (int t = 0; t < NT; ++t) {
        const int buf = t & 1, nbuf = buf ^ 1;
        const bool pf = (t + 1 < NT);
        const bf16_t* sa = &sm.st[buf][0];
        const bf16_t* sb = &sm.st[buf][16384];
        bf16_t* nb = &sm.st[nbuf][0];

        // ---- phase 1
        asm volatile("s_waitcnt vmcnt(4) lgkmcnt(0)" ::: "memory");
        __builtin_amdgcn_s_barrier();
        asm volatile("" ::: "memory");
        if (pf) { ASYNC16(gA0, nb + dA0); ASYNC16(gA0 + 32, nb + dA0 + 512); }
        bf16x8 a0[4][2], b0[2][2];
        #pragma unroll
        for (int i = 0; i < 4; i++)
            #pragma unroll
            for (int ks = 0; ks < 2; ks++)
                a0[i][ks] = *(const bf16x8*)(sa + ((wm * 8 + i) * 2 + ks) * 512 + l * 8);
        #pragma unroll
        for (int j = 0; j < 2; j++)
            #pragma unroll
            for (int ks = 0; ks < 2; ks++)
                b0[j][ks] = *(const bf16x8*)(sb + ((wn * 4 + j) * 2 + ks) * 512 + l * 8);
        __builtin_amdgcn_s_setprio(1);
        #pragma unroll
        for (int i = 0; i < 4; i++)
            #pragma unroll
            for (int j = 0; j < 2; j++) {
                acc[i][j] = MFMA16(a0[i][0], b0[j][0], acc[i][j]);
                acc[i][j] = MFMA16(a0[i][1], b0[j][1], acc[i][j]);
            }
        __builtin_amdgcn_s_setprio(0);

        // ---- phase 2
        if (pf) { asm volatile("s_waitcnt vmcnt(4)" ::: "memory"); }
        else    { asm volatile("s_waitcnt vmcnt(2)" ::: "memory"); }
        __builtin_amdgcn_s_barrier();
        asm volatile("" ::: "memory");
        if (pf) { ASYNC16(gB0, nb + dB0); ASYNC16(gB0 + 32, nb + dB0 + 512); }
        bf16x8 b1[2][2];
        #pragma unroll
        for (int j = 0; j < 2; j++)
            #pragma unroll
            for (int ks = 0; ks < 2; ks++)
                b1[j][ks] = *(const bf16x8*)(sb + ((wn * 4 + 2 + j) * 2 + ks) * 512 + l * 8);
        __builtin_amdgcn_s_setprio(1);
        #pragma unroll
        for (int i = 0; i < 4; i++)
            #pragma unroll
            for (int j = 0; j < 2; j++) {
                acc[i][2 + j] = MFMA16(a0[i][0], b1[j][0], acc[i][2 + j]);
                acc[i][2 + j] = MFMA16(a0[i][1], b1[j][1], acc[i][2 + j]);
            }
        __builtin_amdgcn_s_setprio(0);

        // ---- phase 3
        if (pf) { asm volatile("s_waitcnt vmcnt(4)" ::: "memory"); }
        else    { asm volatile("s_waitcnt vmcnt(0)" ::: "memory"); }
        __builtin_amdgcn_s_barrier();
        asm volatile("" ::: "memory");
        if (pf) { ASYNC16(gB1, nb + dB1); ASYNC16(gB1 + 32, nb + dB1 + 512); }
        bf16x8 a1[4][2];
        #pragma unroll
        for (int i = 0; i < 4; i++)
            #pragma unroll
            for (int ks = 0; ks < 2; ks++)
                a1[i][ks] = *(const bf16x8*)(sa + ((wm * 8 + 4 + i) * 2 + ks) * 512 + l * 8);
        __builtin_amdgcn_s_setprio(1);
        #pragma unroll
        for (int i = 0; i < 4; i++)
            #pragma unroll
            for (int j = 0; j < 2; j++) {
                acc[4 + i][j] = MFMA16(a1[i][0], b0[j][0], acc[4 + i][j]);
                acc[4 + i][j] = MFMA16(a1[i][1], b0[j][1], acc[4 + i][j]);
            }
        __builtin_amdgcn_s_setprio(0);

        // ---- phase 4
        if (pf) {
            ASYNC16(gA1, nb + dA1); ASYNC16(gA1 + 32, nb + dA1 + 512);
            gA0 += 64; gA1 += 64; gB0 += 64; gB1 += 64;
        }
        __builtin_amdgcn_s_setprio(1);
        #pragma unroll
        for (int i = 0; i < 4; i++)
            #pragma unroll
            for (int j = 0; j < 2; j++) {
                acc[4 + i][2 + j] = MFMA16(a1[i][0], b1[j][0], acc[4 + i][2 + j]);
                acc[4 + i][2 + j] = MFMA16(a1[i][1], b1[j][1], acc[4 + i][2 + j]);
            }
        __builtin_amdgcn_s_setprio(0);
    }

    // ------------- epilogue (QKV + fused RoPE) -------------
    const int mbase = tm * 256;
    const int nb2   = tn * 256;
    const int sel   = nb2 >> 11;                // 0=Q 1=K 2=V
    const int hh0   = (nb2 & 2047) >> 7;
    const int bidx  = mbase >> 11;
    const int g   = tid >> 5;
    const int c8  = (tid & 31) * 8;

    if (sel < 2) {
        bf16_t* base = ((sel == 0) ? Qout : Kout) + (size_t)(bidx * NH) * SEQ * HD;
        // Q scale = 1/sqrt(128) * log2(e)  (softmax runs in log2 domain)
        const float qs = (sel == 0) ? 0.12751742770560996f : 1.0f;
        for (int slice = 0; slice < 4; slice++) {
            __syncthreads();
            if (wm == (slice >> 1)) {
                for (int i2 = 0; i2 < 4; i2++) {
                    const int i = (slice & 1) * 4 + i2;
                    for (int j = 0; j < 4; j++)
                        for (int r = 0; r < 4; r++)
                            sm.epi[(i2 * 16 + quad * 4 + r) * 264 + wn * 64 + j * 16 + lane16] =
                                (bf16_t)acc[i][j][r];
                }
            }
            __syncthreads();
            const int head = hh0 + (c8 >> 7);
            const int d0   = c8 & 127;
            for (int p = 0; p < 4; p++) {
                const int rid = p * 16 + g;
                const int s = (mbase & 2047) + slice * 64 + rid;
                bf16x8 v = *(const bf16x8*)&sm.epi[rid * 264 + c8];
                const float pp = (float)pos[bidx * SEQ + s];
                union { bf16_t h8[8]; uint4 u; } o;
                for (int t = 0; t < 4; t++) {
                    const int fi = (d0 >> 1) + t;
                    const float freq = exp2f(-(float)fi * 0.20762050593045857f);
                    const float ang = pp * freq;
                    const float sn = __sinf(ang), cs = __cosf(ang);
                    const float x1 = (float)v[2 * t], x2 = (float)v[2 * t + 1];
                    o.h8[2 * t]     = (bf16_t)((x1 * cs - x2 * sn) * qs);
                    o.h8[2 * t + 1] = (bf16_t)((x1 * sn + x2 * cs) * qs);
                }
                *(uint4*)(base + (size_t)(head * SEQ + s) * HD + d0) = o.u;
            }
        }
    } else {
        const int s0 = mbase & 2047;
        for (int half = 0; half < 4; half++) {
            __syncthreads();
            if (wn == half) {
                for (int i = 0; i < 8; i++)
                    for (int j = 0; j < 4; j++) {
                        union { bf16_t h4[4]; uint2 u; } pk;
                        for (int r = 0; r < 4; r++) pk.h4[r] = (bf16_t)acc[i][j][r];
                        *(uint2*)&sm.epi[(j * 16 + lane16) * 264 + wm * 128 + i * 16 + quad * 4] = pk.u;
                    }
            }
            __syncthreads();
            const int head = hh0 + (half >> 1);
            bf16_t* dstb = Vout + (size_t)(bidx * NH + head) * HD * SEQ;
            for (int p = 0; p < 4; p++) {
                const int rid = p * 16 + g;
                const int dh  = (half & 1) * 64 + rid;
                bf16x8 v = *(const bf16x8*)&sm.epi[rid * 264 + c8];
                *(uint4*)(dstb + (size_t)dh * SEQ + s0 + c8) = *(const uint4*)&v;
            }
        }
    }
}

// ---------------------------------------------------------------- 128x128 GEMM (gemm_out)
union SMemU {
    struct { bf16_t A[3][4096]; bf16_t B[3][4096]; } st;
    bf16_t epi[64 * 136];
};

__global__ __launch_bounds__(256) void gemm_out(const bf16_t* __restrict__ A,
                                                const bf16_t* __restrict__ B,
                                                float* __restrict__ Cout) {
    __shared__ SMemU sm;
    const int tid = threadIdx.x;
    const int w = tid >> 6, l = tid & 63;
    const int lane16 = l & 15, quad = l >> 4;
    const int tm = blockIdx.y, tn = blockIdx.x;
    const int wm = w >> 1, wn = w & 1;

    const bf16_t* pA0 = A + (size_t)(tm * 128 + (2 * w + 0) * 16 + lane16) * KK + quad * 8;
    const bf16_t* pA1 = A + (size_t)(tm * 128 + (2 * w + 1) * 16 + lane16) * KK + quad * 8;
    const bf16_t* pB0 = B + (size_t)(tn * 128 + (2 * w + 0) * 16 + lane16) * KK + quad * 8;
    const bf16_t* pB1 = B + (size_t)(tn * 128 + (2 * w + 1) * 16 + lane16) * KK + quad * 8;

    f32x4 acc[4][4];
    for (int i = 0; i < 4; i++)
        for (int j = 0; j < 4; j++) acc[i][j] = (f32x4){0.f, 0.f, 0.f, 0.f};

    ASYNC16(pA0,      &sm.st.A[0][(2 * w + 0) * 512]);
    ASYNC16(pA1,      &sm.st.A[0][(2 * w + 1) * 512]);
    ASYNC16(pB0,      &sm.st.B[0][(2 * w + 0) * 512]);
    ASYNC16(pB1,      &sm.st.B[0][(2 * w + 1) * 512]);
    ASYNC16(pA0 + 32, &sm.st.A[1][(2 * w + 0) * 512]);
    ASYNC16(pA1 + 32, &sm.st.A[1][(2 * w + 1) * 512]);
    ASYNC16(pB0 + 32, &sm.st.B[1][(2 * w + 0) * 512]);
    ASYNC16(pB1 + 32, &sm.st.B[1][(2 * w + 1) * 512]);

    const bf16_t* qA0 = pA0 + 64;
    const bf16_t* qA1 = pA1 + 64;
    const bf16_t* qB0 = pB0 + 64;
    const bf16_t* qB1 = pB1 + 64;

    const int NT = KK / 32;
    int rdbuf = 0, stbuf = 2;
    for (int t = 0; t < NT; ++t) {
        if (t == NT - 1) { asm volatile("s_waitcnt vmcnt(0) lgkmcnt(0)" ::: "memory"); }
        else             { asm volatile("s_waitcnt vmcnt(4) lgkmcnt(0)" ::: "memory"); }
        __builtin_amdgcn_s_barrier();
        asm volatile("" ::: "memory");
        if (t + 2 < NT) {
            ASYNC16(qA0, &sm.st.A[stbuf][(2 * w + 0) * 512]);
            ASYNC16(qA1, &sm.st.A[stbuf][(2 * w + 1) * 512]);
            ASYNC16(qB0, &sm.st.B[stbuf][(2 * w + 0) * 512]);
            ASYNC16(qB1, &sm.st.B[stbuf][(2 * w + 1) * 512]);
            qA0 += 32; qA1 += 32; qB0 += 32; qB1 += 32;
            stbuf = (stbuf == 2) ? 0 : stbuf + 1;
        }
        const bf16_t* rA = &sm.st.A[rdbuf][wm * 2048 + l * 8];
        const bf16_t* rB = &sm.st.B[rdbuf][wn * 2048 + l * 8];
        bf16x8 af[4], bfr[4];
        for (int i = 0; i < 4; i++) af[i]  = *(const bf16x8*)(rA + i * 512);
        for (int j = 0; j < 4; j++) bfr[j] = *(const bf16x8*)(rB + j * 512);
        for (int i = 0; i < 4; i++)
            for (int j = 0; j < 4; j++)
                acc[i][j] = MFMA16(af[i], bfr[j], acc[i][j]);
        rdbuf = (rdbuf == 2) ? 0 : rdbuf + 1;
    }

    const int mbase = tm * 128 + wm * 64;
    const int nbase = tn * 128 + wn * 64;
    for (int i = 0; i < 4; i++)
        for (int j = 0; j < 4; j++) {
            const int n  = nbase + j * 16 + lane16;
            const int m0 = mbase + i * 16 + quad * 4;
            for (int r = 0; r < 4; r++)
                Cout[(size_t)(m0 + r) * 2048 + n] = acc[i][j][r];
        }
}

// ---------------------------------------------------------------- causal flash attention
// MERGED two-q-tile k-loop: tile B=(31-bt) always active, tile A=(bt) active for
// kb<=bt.  One K/V staging pass (32-bt tiles vs 33 before, -26%), one barrier per
// 64 keys covering up to 2x the MFMA+softmax work.  Softmax in log2 domain (Q is
// pre-scaled by 1/sqrt(128)*log2e in gemm_qkv) -> exp2f directly; T13 threshold
// 11.5 log2-units (bound 2^11.5 ~ 2896, bf16-safe).  Per-block work balanced:
// (bt+1) two-tile + (31-2bt) one-tile iters = 33 tile-iterations for every bt.
__device__ __forceinline__ void sm_pv(f32x4* sacc, float& m_s, float& l_s, f32x4* o,
                                      bf16_t* pbw, const bf16_t* vtc,
                                      int lane16, int quad, int l) {
    float rmnt[4];
    for (int nt = 0; nt < 4; nt++)
        rmnt[nt] = fmaxf(fmaxf(sacc[nt][0], sacc[nt][1]),
                         fmaxf(sacc[nt][2], sacc[nt][3]));
    float rowmax = fmaxf(fmaxf(rmnt[0], rmnt[1]), fmaxf(rmnt[2], rmnt[3]));
    rowmax = fmaxf(rowmax, __shfl_xor(rowmax, 16, 64));
    rowmax = fmaxf(rowmax, __shfl_xor(rowmax, 32, 64));
    float a = 1.f;
    const bool noresc = __all(rowmax <= m_s + 11.5f) != 0;   // T13, log2 units
    if (!noresc) {
        const float mnew = fmaxf(m_s, rowmax);
        a = exp2f(m_s - mnew);                  // first iter: exp2(-inf)=0
        m_s = mnew;
    }
    float ssum = 0.f;
    for (int nt = 0; nt < 4; nt++) {
        union { bf16_t h4[4]; uint2 u; } pk;
        for (int r = 0; r < 4; r++) {
            const float e = exp2f(sacc[nt][r] - m_s);
            ssum += e;
            pk.h4[r] = (bf16_t)e;
        }
        const int addr = (nt >> 1) * 512 +
                         (((nt & 1) * 2 + (quad >> 1)) * 16 + lane16) * 8 +
                         (quad & 1) * 4;
        *(uint2*)&pbw[addr] = pk.u;
    }
    ssum += __shfl_xor(ssum, 16, 64);
    ssum += __shfl_xor(ssum, 32, 64);
    l_s = l_s * a + ssum;
    if (!noresc) {
        float ar[4];
        for (int r = 0; r < 4; r++) ar[r] = __shfl(a, (quad << 2) | r, 16);
        for (int dt = 0; dt < 8; dt++)
            for (int r = 0; r < 4; r++) o[dt][r] *= ar[r];
    }
    __builtin_amdgcn_s_setprio(1);              // T5: PV MFMA cluster
    for (int kk = 0; kk < 2; kk++) {
        bf16x8 pf = *(const bf16x8*)&pbw[kk * 512 + l * 8];
        for (int dt = 0; dt < 8; dt++) {
            bf16x8 vf = *(const bf16x8*)&vtc[(dt * 2 + kk) * 512 + l * 8];
            o[dt] = MFMA16(pf, vf, o[dt]);
        }
    }
    __builtin_amdgcn_s_setprio(0);
}

__global__ __launch_bounds__(256, 2) void attn_kernel(const bf16_t* __restrict__ Q,
                                                      const bf16_t* __restrict__ K,
                                                      const bf16_t* __restrict__ Vt,
                                                      bf16_t* __restrict__ ctx) {
    const int flat = blockIdx.x;
    const int bh = flat & 31;
    const int bt = flat >> 5;                   // 0..15
    const int h = bh & 15, b = bh >> 4;
    const bf16_t* Qh = Q  + (size_t)bh * SEQ * HD;
    const bf16_t* Kh = K  + (size_t)bh * SEQ * HD;
    const bf16_t* Vh = Vt + (size_t)bh * HD * SEQ;

    const int tid = threadIdx.x;
    const int w = tid >> 6, l = tid & 63;
    const int lane16 = l & 15, quad = l >> 4;

    __shared__ bf16_t kt[2][16 * 512];
    __shared__ bf16_t vt[2][16 * 512];
    __shared__ bf16_t pbuf[4][1024];

    const int qtA = bt;                         // short tile (kb <= qtA)
    const int qtB = 31 - bt;                    // long tile (always active)
    const int q0A = qtA * 64 + w * 16;
    const int q0B = qtB * 64 + w * 16;

    bf16x8 qfA[4], qfB[4];
    {
        const bf16_t* qra = Qh + (size_t)(q0A + lane16) * HD + quad * 8;
        const bf16_t* qrb = Qh + (size_t)(q0B + lane16) * HD + quad * 8;
        for (int kc = 0; kc < 4; kc++) {
            qfA[kc] = *(const bf16x8*)(qra + kc * 32);
            qfB[kc] = *(const bf16x8*)(qrb + kc * 32);
        }
    }

    f32x4 oA[8], oB[8];
    for (int dt = 0; dt < 8; dt++) {
        oA[dt] = (f32x4){0.f, 0.f, 0.f, 0.f};
        oB[dt] = (f32x4){0.f, 0.f, 0.f, 0.f};
    }
    float mA = -INFINITY, lA = 0.f;
    float mB = -INFINITY, lB = 0.f;

    // prologue: stage kb=0 into buffer 0
    for (int ii = 0; ii < 4; ii++) {
        const int f = w * 4 + ii;
        const int nt = f >> 2, kc = f & 3;
        ASYNC16(Kh + (size_t)(nt * 16 + lane16) * HD + kc * 32 + quad * 8, &kt[0][f * 512]);
        const int dt = f >> 1, kk = f & 1;
        ASYNC16(Vh + (size_t)(dt * 16 + lane16) * SEQ + kk * 32 + quad * 8, &vt[0][f * 512]);
    }

    int cur = 0;
    for (int kb = 0; kb <= qtB; kb++) {
        const int k0 = kb * 64;
        __syncthreads();                        // drains kb's staging (issued 1 iter ago)
        if (kb < qtB) {
            const int kn = k0 + 64;
            for (int ii = 0; ii < 4; ii++) {
                const int f = w * 4 + ii;
                const int nt = f >> 2, kc = f & 3;
                ASYNC16(Kh + (size_t)(kn + nt * 16 + lane16) * HD + kc * 32 + quad * 8,
                        &kt[1 - cur][f * 512]);
                const int dt = f >> 1, kk = f & 1;
                ASYNC16(Vh + (size_t)(dt * 16 + lane16) * SEQ + kn + kk * 32 + quad * 8,
                        &vt[1 - cur][f * 512]);
            }
        }
        const bf16_t* ktc = kt[cur];
        const bf16_t* vtc = vt[cur];

        // ---------- tile B (always active) ----------
        {
            f32x4 sacc[4];
            for (int nt = 0; nt < 4; nt++) sacc[nt] = (f32x4){0.f, 0.f, 0.f, 0.f};
            __builtin_amdgcn_s_setprio(1);
            for (int nt = 0; nt < 4; nt++)
                for (int kc = 0; kc < 4; kc++) {
                    bf16x8 kf = *(const bf16x8*)&ktc[(nt * 4 + kc) * 512 + l * 8];
                    sacc[nt] = MFMA16(kf, qfB[kc], sacc[nt]);
                }
            __builtin_amdgcn_s_setprio(0);
            if (kb == qtB) {
                const int qg = q0B + lane16;
                for (int nt = 0; nt < 4; nt++)
                    for (int r = 0; r < 4; r++) {
                        const int kg = k0 + nt * 16 + quad * 4 + r;
                        if (kg > qg) sacc[nt][r] = -INFINITY;
                    }
            }
            sm_pv(sacc, mB, lB, oB, pbuf[w], vtc, lane16, quad, l);
        }

        // ---------- tile A (active while kb <= qtA; block-uniform guard) ----------
        if (kb <= qtA) {
            f32x4 sacc[4];
            for (int nt = 0; nt < 4; nt++) sacc[nt] = (f32x4){0.f, 0.f, 0.f, 0.f};
            __builtin_amdgcn_s_setprio(1);
            for (int nt = 0; nt < 4; nt++)
                for (int kc = 0; kc < 4; kc++) {
                    bf16x8 kf = *(const bf16x8*)&ktc[(nt * 4 + kc) * 512 + l * 8];
                    sacc[nt] = MFMA16(kf, qfA[kc], sacc[nt]);
                }
            __builtin_amdgcn_s_setprio(0);
            if (kb == qtA) {
                const int qg = q0A + lane16;
                for (int nt = 0; nt < 4; nt++)
                    for (int r = 0; r < 4; r++) {
                        const int kg = k0 + nt * 16 + quad * 4 + r;
                        if (kg > qg) sacc[nt][r] = -INFINITY;
                    }
            }
            sm_pv(sacc, mA, lA, oA, pbuf[w], vtc, lane16, quad, l);
        }
        cur ^= 1;
    }

    // ---------- write out both tiles ----------
    {
        float inv[4];
        for (int r = 0; r < 4; r++) inv[r] = 1.0f / __shfl(lA, (quad << 2) | r, 16);
        for (int r = 0; r < 4; r++) {
            const int qg = q0A + quad * 4 + r;
            bf16_t* dst = ctx + ((size_t)(b * SEQ + qg)) * (NH * HD) + h * HD;
            for (int dt = 0; dt < 8; dt++)
                dst[dt * 16 + lane16] = (bf16_t)(oA[dt][r] * inv[r]);
        }
    }
    {
        float inv[4];
        for (int r = 0; r < 4; r++) inv[r] = 1.0f / __shfl(lB, (quad << 2) | r, 16);
        for (int r = 0; r < 4; r++) {
            const int qg = q0B + quad * 4 + r;
            bf16_t* dst = ctx + ((size_t)(b * SEQ + qg)) * (NH * HD) + h * HD;
            for (int dt = 0; dt < 8; dt++)
                dst[dt * 16 + lane16] = (bf16_t)(oB[dt][r] * inv[r]);
        }
    }
}

// ---------------------------------------------------------------- launch
extern "C" void kernel_launch(void* const* d_in, const int* in_sizes, int n_in,
                              void* d_out, int out_size, void* d_ws, size_t ws_size,
                              hipStream_t stream) {
    const float* x  = (const float*)d_in[0];
    const int* pos  = (const int*)d_in[1];
    const float* Wq = (const float*)d_in[2];
    const float* Wk = (const float*)d_in[3];
    const float* Wv = (const float*)d_in[4];
    const float* Wo = (const float*)d_in[5];

    char* ws = (char*)d_ws;
    bf16_t* xb   = (bf16_t*)(ws);
    bf16_t* wqkv = (bf16_t*)(ws + (16u << 20));   // [6144,2048]
    bf16_t* wob  = (bf16_t*)(ws + (40u << 20));
    bf16_t* Qb   = (bf16_t*)(ws + (48u << 20));
    bf16_t* Kb   = (bf16_t*)(ws + (64u << 20));
    bf16_t* Vt   = (bf16_t*)(ws + (80u << 20));
    bf16_t* ctx  = (bf16_t*)(ws + (96u << 20));

    cast_all<<<24576, 256, 0, stream>>>(x, Wq, Wk, Wv, Wo, xb, wqkv, wob);

    dim3 gq(6144 / 256, MM / 256);
    gemm_qkv<<<gq, 512, 0, stream>>>(xb, wqkv, Qb, Kb, Vt, pos);

    attn_kernel<<<512, 256, 0, stream>>>(Qb, Kb, Vt, ctx);

    dim3 gg(2048 / 128, MM / 128);
    gemm_out<<<gg, 256, 0, stream>>>(ctx, wob, (float*)d_out);
}

// Round 9
// 414.035 us; speedup vs baseline: 1.0344x; 1.0344x over previous
//
#include <hip/hip_runtime.h>
#include <cstdint>
#include <cstddef>

typedef __bf16 bf16_t;
typedef __bf16 bf16x8 __attribute__((ext_vector_type(8)));
typedef float  f32x4  __attribute__((ext_vector_type(4)));

#define SEQ 2048
#define NH  16
#define HD  128
#define MM  4096   // b*s rows
#define KK  2048

// async global->LDS, 16B per lane, LDS dest = wave-uniform base + lane*16
#define ASYNC16(g, l) __builtin_amdgcn_global_load_lds( \
    (const __attribute__((address_space(1))) void*)(g), \
    (__attribute__((address_space(3))) void*)(l), 16, 0, 0)

#define MFMA16(a, b, c) __builtin_amdgcn_mfma_f32_16x16x32_bf16((a), (b), (c), 0, 0, 0)

// ---------------------------------------------------------------- one cast kernel
__global__ __launch_bounds__(256) void cast_all(const float* __restrict__ x,
                                                const float* __restrict__ Wq,
                                                const float* __restrict__ Wk,
                                                const float* __restrict__ Wv,
                                                const float* __restrict__ Wo,
                                                bf16_t* __restrict__ xb,
                                                bf16_t* __restrict__ wqkv,
                                                bf16_t* __restrict__ wob) {
    int i = blockIdx.x * 256 + threadIdx.x;     // 0..6M-1 float4 groups
    const float* src;
    bf16_t* dst;
    int off;
    if (i < 2097152) { src = x; dst = xb; off = i; }
    else {
        int j = i - 2097152;
        int sel = j >> 20; off = j & 0xFFFFF;
        if (sel < 3) { src = (sel == 0) ? Wq : (sel == 1) ? Wk : Wv; dst = wqkv + (size_t)sel * 4194304; }
        else         { src = Wo; dst = wob; }
    }
    float4 v = ((const float4*)src)[off];
    union { bf16_t h[4]; uint2 u; } t;
    t.h[0] = (bf16_t)v.x; t.h[1] = (bf16_t)v.y;
    t.h[2] = (bf16_t)v.z; t.h[3] = (bf16_t)v.w;
    ((uint2*)dst)[off] = t.u;
}

// ================================================================ 256x256 QKV GEMM, 2-barrier/K-tile
// Staging order per tile: A0,B0,B1,A1 (2 gload_lds each).  Certification:
//  barrier1 @ vmcnt(2): A0,B0,B1 of tile t in LDS (only A1 outstanding)
//    -> phase 1 reads a0,b0 AND b1 (b1 consumed one phase later)
//  barrier2 @ vmcnt(4): A1 of tile t in LDS (A0',B0' of t+1 outstanding)
//    -> a1 read under Q2's MFMA; Q2,Q3,Q4 run back-to-back.
// Writes always target nbuf (!= read buf); all reads of tile t-1 are
// register-consumed before their wave reaches tile t's barrier1 -> WAR-safe.
union SMemQ8 {
    bf16_t st[2][32768];     // 128 KB: [buf][ A: frag(mi,ks)*512 | B at +16384 ]
    bf16_t epi[64 * 264];    // epilogue transpose
};

__global__ __launch_bounds__(512, 2) void gemm_qkv(const bf16_t* __restrict__ A,
                                                   const bf16_t* __restrict__ B,
                                                   bf16_t* __restrict__ Qout,
                                                   bf16_t* __restrict__ Kout,
                                                   bf16_t* __restrict__ Vout,
                                                   const int* __restrict__ pos) {
    __shared__ SMemQ8 sm;
    const int tid = threadIdx.x;
    const int w = tid >> 6, l = tid & 63;       // 8 waves
    const int lane16 = l & 15, quad = l >> 4;
    const int tm = blockIdx.y, tn = blockIdx.x; // 256-row / 256-col tiles
    const int wm = w >> 2, wn = w & 3;          // 2M x 4N wave grid

    const int miA0 = wm * 8 + wn;
    const int miA1 = miA0 + 4;
    const int niB0 = (w >> 1) * 4 + (w & 1);
    const int niB1 = niB0 + 2;

    const bf16_t* gA0 = A + (size_t)(tm * 256 + miA0 * 16 + lane16) * KK + quad * 8;
    const bf16_t* gA1 = A + (size_t)(tm * 256 + miA1 * 16 + lane16) * KK + quad * 8;
    const bf16_t* gB0 = B + (size_t)(tn * 256 + niB0 * 16 + lane16) * KK + quad * 8;
    const bf16_t* gB1 = B + (size_t)(tn * 256 + niB1 * 16 + lane16) * KK + quad * 8;

    const int dA0 = miA0 * 1024;
    const int dA1 = miA1 * 1024;
    const int dB0 = 16384 + niB0 * 1024;
    const int dB1 = 16384 + niB1 * 1024;

    f32x4 acc[8][4];
    #pragma unroll
    for (int i = 0; i < 8; i++)
        #pragma unroll
        for (int j = 0; j < 4; j++) acc[i][j] = (f32x4){0.f, 0.f, 0.f, 0.f};

    // prologue: stage tile 0 in certification order A0,B0,B1,A1
    ASYNC16(gA0,      &sm.st[0][dA0]);
    ASYNC16(gA0 + 32, &sm.st[0][dA0 + 512]);
    ASYNC16(gB0,      &sm.st[0][dB0]);
    ASYNC16(gB0 + 32, &sm.st[0][dB0 + 512]);
    ASYNC16(gB1,      &sm.st[0][dB1]);
    ASYNC16(gB1 + 32, &sm.st[0][dB1 + 512]);
    ASYNC16(gA1,      &sm.st[0][dA1]);
    ASYNC16(gA1 + 32, &sm.st[0][dA1 + 512]);
    gA0 += 64; gA1 += 64; gB0 += 64; gB1 += 64;

    const int NT = KK / 64;                     // 32 K-tiles
    for (int t = 0; t < NT; ++t) {
        const int buf = t & 1, nbuf = buf ^ 1;
        const bool pf = (t + 1 < NT);
        const bf16_t* sa = &sm.st[buf][0];
        const bf16_t* sb = &sm.st[buf][16384];
        bf16_t* nb = &sm.st[nbuf][0];

        // ---- barrier 1: certifies A0,B0,B1 of tile t
        asm volatile("s_waitcnt vmcnt(2) lgkmcnt(0)" ::: "memory");
        __builtin_amdgcn_s_barrier();
        asm volatile("" ::: "memory");
        if (pf) { ASYNC16(gA0, nb + dA0); ASYNC16(gA0 + 32, nb + dA0 + 512); }

        bf16x8 a0[4][2], b0[2][2], b1[2][2], a1[4][2];
        #pragma unroll
        for (int i = 0; i < 4; i++)
            #pragma unroll
            for (int ks = 0; ks < 2; ks++)
                a0[i][ks] = *(const bf16x8*)(sa + ((wm * 8 + i) * 2 + ks) * 512 + l * 8);
        #pragma unroll
        for (int j = 0; j < 2; j++)
            #pragma unroll
            for (int ks = 0; ks < 2; ks++) {
                b0[j][ks] = *(const bf16x8*)(sb + ((wn * 4 + j) * 2 + ks) * 512 + l * 8);
                b1[j][ks] = *(const bf16x8*)(sb + ((wn * 4 + 2 + j) * 2 + ks) * 512 + l * 8);
            }
        // Q1: a0 x b0
        __builtin_amdgcn_s_setprio(1);
        #pragma unroll
        for (int i = 0; i < 4; i++)
            #pragma unroll
            for (int j = 0; j < 2; j++) {
                acc[i][j] = MFMA16(a0[i][0], b0[j][0], acc[i][j]);
                acc[i][j] = MFMA16(a0[i][1], b0[j][1], acc[i][j]);
            }
        __builtin_amdgcn_s_setprio(0);
        if (pf) { ASYNC16(gB0, nb + dB0); ASYNC16(gB0 + 32, nb + dB0 + 512); }

        // ---- barrier 2: certifies A1 of tile t
        if (pf) { asm volatile("s_waitcnt vmcnt(4)" ::: "memory"); }
        else    { asm volatile("s_waitcnt vmcnt(0)" ::: "memory"); }
        __builtin_amdgcn_s_barrier();
        asm volatile("" ::: "memory");
        if (pf) { ASYNC16(gB1, nb + dB1); ASYNC16(gB1 + 32, nb + dB1 + 512); }
        #pragma unroll
        for (int i = 0; i < 4; i++)
            #pragma unroll
            for (int ks = 0; ks < 2; ks++)
                a1[i][ks] = *(const bf16x8*)(sa + ((wm * 8 + 4 + i) * 2 + ks) * 512 + l * 8);
        // Q2: a0 x b1 (b1 preloaded last phase; a1 reads land underneath)
        __builtin_amdgcn_s_setprio(1);
        #pragma unroll
        for (int i = 0; i < 4; i++)
            #pragma unroll
            for (int j = 0; j < 2; j++) {
                acc[i][2 + j] = MFMA16(a0[i][0], b1[j][0], acc[i][2 + j]);
                acc[i][2 + j] = MFMA16(a0[i][1], b1[j][1], acc[i][2 + j]);
            }
        __builtin_amdgcn_s_setprio(0);
        if (pf) {
            ASYNC16(gA1, nb + dA1); ASYNC16(gA1 + 32, nb + dA1 + 512);
            gA0 += 64; gA1 += 64; gB0 += 64; gB1 += 64;
        }
        // Q3 + Q4: a1 x b0, a1 x b1 — back-to-back MFMA
        __builtin_amdgcn_s_setprio(1);
        #pragma unroll
        for (int i = 0; i < 4; i++)
            #pragma unroll
            for (int j = 0; j < 2; j++) {
                acc[4 + i][j]     = MFMA16(a1[i][0], b0[j][0], acc[4 + i][j]);
                acc[4 + i][j]     = MFMA16(a1[i][1], b0[j][1], acc[4 + i][j]);
                acc[4 + i][2 + j] = MFMA16(a1[i][0], b1[j][0], acc[4 + i][2 + j]);
                acc[4 + i][2 + j] = MFMA16(a1[i][1], b1[j][1], acc[4 + i][2 + j]);
            }
        __builtin_amdgcn_s_setprio(0);
    }

    // ------------- epilogue (QKV + fused RoPE), R5/R7-verified layout -------------
    const int mbase = tm * 256;
    const int nb2   = tn * 256;
    const int sel   = nb2 >> 11;                // 0=Q 1=K 2=V
    const int hh0   = (nb2 & 2047) >> 7;
    const int bidx  = mbase >> 11;
    const int g   = tid >> 5;
    const int c8  = (tid & 31) * 8;

    if (sel < 2) {
        bf16_t* base = ((sel == 0) ? Qout : Kout) + (size_t)(bidx * NH) * SEQ * HD;
        const float qs = (sel == 0) ? 0.08838834764831845f : 1.0f;  // 1/sqrt(128) on Q
        for (int slice = 0; slice < 4; slice++) {
            __syncthreads();
            if (wm == (slice >> 1)) {
                for (int i2 = 0; i2 < 4; i2++) {
                    const int i = (slice & 1) * 4 + i2;
                    for (int j = 0; j < 4; j++)
                        for (int r = 0; r < 4; r++)
                            sm.epi[(i2 * 16 + quad * 4 + r) * 264 + wn * 64 + j * 16 + lane16] =
                                (bf16_t)acc[i][j][r];
                }
            }
            __syncthreads();
            const int head = hh0 + (c8 >> 7);
            const int d0   = c8 & 127;
            for (int p = 0; p < 4; p++) {
                const int rid = p * 16 + g;
                const int s = (mbase & 2047) + slice * 64 + rid;
                bf16x8 v = *(const bf16x8*)&sm.epi[rid * 264 + c8];
                const float pp = (float)pos[bidx * SEQ + s];
                union { bf16_t h8[8]; uint4 u; } o;
                for (int t = 0; t < 4; t++) {
                    const int fi = (d0 >> 1) + t;
                    const float freq = exp2f(-(float)fi * 0.20762050593045857f);
                    const float ang = pp * freq;
                    const float sn = __sinf(ang), cs = __cosf(ang);
                    const float x1 = (float)v[2 * t], x2 = (float)v[2 * t + 1];
                    o.h8[2 * t]     = (bf16_t)((x1 * cs - x2 * sn) * qs);
                    o.h8[2 * t + 1] = (bf16_t)((x1 * sn + x2 * cs) * qs);
                }
                *(uint4*)(base + (size_t)(head * SEQ + s) * HD + d0) = o.u;
            }
        }
    } else {
        const int s0 = mbase & 2047;
        for (int half = 0; half < 4; half++) {
            __syncthreads();
            if (wn == half) {
                for (int i = 0; i < 8; i++)
                    for (int j = 0; j < 4; j++) {
                        union { bf16_t h4[4]; uint2 u; } pk;
                        for (int r = 0; r < 4; r++) pk.h4[r] = (bf16_t)acc[i][j][r];
                        *(uint2*)&sm.epi[(j * 16 + lane16) * 264 + wm * 128 + i * 16 + quad * 4] = pk.u;
                    }
            }
            __syncthreads();
            const int head = hh0 + (half >> 1);
            bf16_t* dstb = Vout + (size_t)(bidx * NH + head) * HD * SEQ;
            for (int p = 0; p < 4; p++) {
                const int rid = p * 16 + g;
                const int dh  = (half & 1) * 64 + rid;
                bf16x8 v = *(const bf16x8*)&sm.epi[rid * 264 + c8];
                *(uint4*)(dstb + (size_t)dh * SEQ + s0 + c8) = *(const uint4*)&v;
            }
        }
    }
}

// ---------------------------------------------------------------- 128x128 GEMM (gemm_out)
union SMemU {
    struct { bf16_t A[3][4096]; bf16_t B[3][4096]; } st;
    bf16_t epi[64 * 136];
};

__global__ __launch_bounds__(256) void gemm_out(const bf16_t* __restrict__ A,
                                                const bf16_t* __restrict__ B,
                                                float* __restrict__ Cout) {
    __shared__ SMemU sm;
    const int tid = threadIdx.x;
    const int w = tid >> 6, l = tid & 63;
    const int lane16 = l & 15, quad = l >> 4;
    const int tm = blockIdx.y, tn = blockIdx.x;
    const int wm = w >> 1, wn = w & 1;

    const bf16_t* pA0 = A + (size_t)(tm * 128 + (2 * w + 0) * 16 + lane16) * KK + quad * 8;
    const bf16_t* pA1 = A + (size_t)(tm * 128 + (2 * w + 1) * 16 + lane16) * KK + quad * 8;
    const bf16_t* pB0 = B + (size_t)(tn * 128 + (2 * w + 0) * 16 + lane16) * KK + quad * 8;
    const bf16_t* pB1 = B + (size_t)(tn * 128 + (2 * w + 1) * 16 + lane16) * KK + quad * 8;

    f32x4 acc[4][4];
    for (int i = 0; i < 4; i++)
        for (int j = 0; j < 4; j++) acc[i][j] = (f32x4){0.f, 0.f, 0.f, 0.f};

    ASYNC16(pA0,      &sm.st.A[0][(2 * w + 0) * 512]);
    ASYNC16(pA1,      &sm.st.A[0][(2 * w + 1) * 512]);
    ASYNC16(pB0,      &sm.st.B[0][(2 * w + 0) * 512]);
    ASYNC16(pB1,      &sm.st.B[0][(2 * w + 1) * 512]);
    ASYNC16(pA0 + 32, &sm.st.A[1][(2 * w + 0) * 512]);
    ASYNC16(pA1 + 32, &sm.st.A[1][(2 * w + 1) * 512]);
    ASYNC16(pB0 + 32, &sm.st.B[1][(2 * w + 0) * 512]);
    ASYNC16(pB1 + 32, &sm.st.B[1][(2 * w + 1) * 512]);

    const bf16_t* qA0 = pA0 + 64;
    const bf16_t* qA1 = pA1 + 64;
    const bf16_t* qB0 = pB0 + 64;
    const bf16_t* qB1 = pB1 + 64;

    const int NT = KK / 32;
    int rdbuf = 0, stbuf = 2;
    for (int t = 0; t < NT; ++t) {
        if (t == NT - 1) { asm volatile("s_waitcnt vmcnt(0) lgkmcnt(0)" ::: "memory"); }
        else             { asm volatile("s_waitcnt vmcnt(4) lgkmcnt(0)" ::: "memory"); }
        __builtin_amdgcn_s_barrier();
        asm volatile("" ::: "memory");
        if (t + 2 < NT) {
            ASYNC16(qA0, &sm.st.A[stbuf][(2 * w + 0) * 512]);
            ASYNC16(qA1, &sm.st.A[stbuf][(2 * w + 1) * 512]);
            ASYNC16(qB0, &sm.st.B[stbuf][(2 * w + 0) * 512]);
            ASYNC16(qB1, &sm.st.B[stbuf][(2 * w + 1) * 512]);
            qA0 += 32; qA1 += 32; qB0 += 32; qB1 += 32;
            stbuf = (stbuf == 2) ? 0 : stbuf + 1;
        }
        const bf16_t* rA = &sm.st.A[rdbuf][wm * 2048 + l * 8];
        const bf16_t* rB = &sm.st.B[rdbuf][wn * 2048 + l * 8];
        bf16x8 af[4], bfr[4];
        for (int i = 0; i < 4; i++) af[i]  = *(const bf16x8*)(rA + i * 512);
        for (int j = 0; j < 4; j++) bfr[j] = *(const bf16x8*)(rB + j * 512);
        for (int i = 0; i < 4; i++)
            for (int j = 0; j < 4; j++)
                acc[i][j] = MFMA16(af[i], bfr[j], acc[i][j]);
        rdbuf = (rdbuf == 2) ? 0 : rdbuf + 1;
    }

    const int mbase = tm * 128 + wm * 64;
    const int nbase = tn * 128 + wn * 64;
    for (int i = 0; i < 4; i++)
        for (int j = 0; j < 4; j++) {
            const int n  = nbase + j * 16 + lane16;
            const int m0 = mbase + i * 16 + quad * 4;
            for (int r = 0; r < 4; r++)
                Cout[(size_t)(m0 + r) * 2048 + n] = acc[i][j][r];
        }
}

// ---------------------------------------------------------------- causal flash attention
// (reverted to the harness-verified 414 us version: two independent q-tile
//  passes, __expf softmax, T13 defer-max @8, tree row-max, T5 setprio)
__global__ __launch_bounds__(256) void attn_kernel(const bf16_t* __restrict__ Q,
                                                   const bf16_t* __restrict__ K,
                                                   const bf16_t* __restrict__ Vt,
                                                   bf16_t* __restrict__ ctx) {
    const int flat = blockIdx.x;
    const int bh = flat & 31;
    const int bt = flat >> 5;                   // 0..15
    const int h = bh & 15, b = bh >> 4;
    const bf16_t* Qh = Q  + (size_t)bh * SEQ * HD;
    const bf16_t* Kh = K  + (size_t)bh * SEQ * HD;
    const bf16_t* Vh = Vt + (size_t)bh * HD * SEQ;

    const int tid = threadIdx.x;
    const int w = tid >> 6, l = tid & 63;
    const int lane16 = l & 15, quad = l >> 4;

    __shared__ bf16_t kt[2][16 * 512];
    __shared__ bf16_t vt[2][16 * 512];
    __shared__ bf16_t pbuf[4][1024];

    for (int half = 0; half < 2; half++) {
        const int qt = half ? (31 - bt) : bt;   // q-tile of 64 rows
        const int q0 = qt * 64 + w * 16;

        bf16x8 qf[4];
        {
            const bf16_t* qrow = Qh + (size_t)(q0 + lane16) * HD + quad * 8;
            for (int kc = 0; kc < 4; kc++) qf[kc] = *(const bf16x8*)(qrow + kc * 32);
        }

        f32x4 o[8];
        for (int dt = 0; dt < 8; dt++) o[dt] = (f32x4){0.f, 0.f, 0.f, 0.f};
        float m_s = -INFINITY, l_s = 0.f;       // per-lane: row q = q0 + lane16

        __syncthreads();
        for (int ii = 0; ii < 4; ii++) {
            const int f = w * 4 + ii;
            const int nt = f >> 2, kc = f & 3;
            ASYNC16(Kh + (size_t)(nt * 16 + lane16) * HD + kc * 32 + quad * 8, &kt[0][f * 512]);
            const int dt = f >> 1, kk = f & 1;
            ASYNC16(Vh + (size_t)(dt * 16 + lane16) * SEQ + kk * 32 + quad * 8, &vt[0][f * 512]);
        }

        int cur = 0;
        for (int kb = 0; kb <= qt; kb++) {
            const int k0 = kb * 64;
            __syncthreads();
            if (kb < qt) {
                const int kn = k0 + 64;
                for (int ii = 0; ii < 4; ii++) {
                    const int f = w * 4 + ii;
                    const int nt = f >> 2, kc = f & 3;
                    ASYNC16(Kh + (size_t)(kn + nt * 16 + lane16) * HD + kc * 32 + quad * 8,
                            &kt[1 - cur][f * 512]);
                    const int dt = f >> 1, kk = f & 1;
                    ASYNC16(Vh + (size_t)(dt * 16 + lane16) * SEQ + kn + kk * 32 + quad * 8,
                            &vt[1 - cur][f * 512]);
                }
            }
            const bf16_t* ktc = kt[cur];
            const bf16_t* vtc = vt[cur];

            f32x4 sacc[4];
            for (int nt = 0; nt < 4; nt++) sacc[nt] = (f32x4){0.f, 0.f, 0.f, 0.f};
            __builtin_amdgcn_s_setprio(1);      // T5: favor this wave while MFMA cluster issues
            for (int nt = 0; nt < 4; nt++)
                for (int kc = 0; kc < 4; kc++) {
                    bf16x8 kf = *(const bf16x8*)&ktc[(nt * 4 + kc) * 512 + l * 8];
                    sacc[nt] = MFMA16(kf, qf[kc], sacc[nt]);
                }
            __builtin_amdgcn_s_setprio(0);
            if (kb == qt) {
                const int qg = q0 + lane16;
                for (int nt = 0; nt < 4; nt++)
                    for (int r = 0; r < 4; r++) {
                        const int kg = k0 + nt * 16 + quad * 4 + r;
                        if (kg > qg) sacc[nt][r] = -INFINITY;
                    }
            }
            // row-max reduce as a tree (depth 4+2; exposes v_max3 fusion — T17)
            float rmnt[4];
            for (int nt = 0; nt < 4; nt++)
                rmnt[nt] = fmaxf(fmaxf(sacc[nt][0], sacc[nt][1]),
                                 fmaxf(sacc[nt][2], sacc[nt][3]));
            float rowmax = fmaxf(fmaxf(rmnt[0], rmnt[1]), fmaxf(rmnt[2], rmnt[3]));
            rowmax = fmaxf(rowmax, __shfl_xor(rowmax, 16, 64));
            rowmax = fmaxf(rowmax, __shfl_xor(rowmax, 32, 64));

            // T13 defer-max: skip the O-rescale when no row grew by >8 ln-units
            float a = 1.f;
            const bool noresc = __all(rowmax <= m_s + 8.f) != 0;
            if (!noresc) {
                const float mnew = fmaxf(m_s, rowmax);
                a = __expf(m_s - mnew);         // first iter: exp(-inf)=0
                m_s = mnew;
            }
            float ssum = 0.f;
            for (int nt = 0; nt < 4; nt++) {
                union { bf16_t h4[4]; uint2 u; } pk;
                for (int r = 0; r < 4; r++) {
                    const float e = __expf(sacc[nt][r] - m_s);
                    ssum += e;
                    pk.h4[r] = (bf16_t)e;
                }
                const int addr = (nt >> 1) * 512 +
                                 (((nt & 1) * 2 + (quad >> 1)) * 16 + lane16) * 8 +
                                 (quad & 1) * 4;
                *(uint2*)&pbuf[w][addr] = pk.u;
            }
            ssum += __shfl_xor(ssum, 16, 64);
            ssum += __shfl_xor(ssum, 32, 64);
            l_s = l_s * a + ssum;

            if (!noresc) {
                float ar[4];
                for (int r = 0; r < 4; r++) ar[r] = __shfl(a, (quad << 2) | r, 16);
                for (int dt = 0; dt < 8; dt++)
                    for (int r = 0; r < 4; r++) o[dt][r] *= ar[r];
            }
            __builtin_amdgcn_s_setprio(1);      // T5: PV MFMA cluster
            for (int kk = 0; kk < 2; kk++) {
                bf16x8 pf = *(const bf16x8*)&pbuf[w][kk * 512 + l * 8];
                for (int dt = 0; dt < 8; dt++) {
                    bf16x8 vf = *(const bf16x8*)&vtc[(dt * 2 + kk) * 512 + l * 8];
                    o[dt] = MFMA16(pf, vf, o[dt]);
                }
            }
            __builtin_amdgcn_s_setprio(0);
            cur ^= 1;
        }

        float inv[4];
        for (int r = 0; r < 4; r++) inv[r] = 1.0f / __shfl(l_s, (quad << 2) | r, 16);
        for (int r = 0; r < 4; r++) {
            const int qg = q0 + quad * 4 + r;
            bf16_t* dst = ctx + ((size_t)(b * SEQ + qg)) * (NH * HD) + h * HD;
            for (int dt = 0; dt < 8; dt++)
                dst[dt * 16 + lane16] = (bf16_t)(o[dt][r] * inv[r]);
        }
        __syncthreads();
    }
}

// ---------------------------------------------------------------- launch
extern "C" void kernel_launch(void* const* d_in, const int* in_sizes, int n_in,
                              void* d_out, int out_size, void* d_ws, size_t ws_size,
                              hipStream_t stream) {
    const float* x  = (const float*)d_in[0];
    const int* pos  = (const int*)d_in[1];
    const float* Wq = (const float*)d_in[2];
    const float* Wk = (const float*)d_in[3];
    const float* Wv = (const float*)d_in[4];
    const float* Wo = (const float*)d_in[5];

    char* ws = (char*)d_ws;
    bf16_t* xb   = (bf16_t*)(ws);
    bf16_t* wqkv = (bf16_t*)(ws + (16u << 20));   // [6144,2048]
    bf16_t* wob  = (bf16_t*)(ws + (40u << 20));
    bf16_t* Qb   = (bf16_t*)(ws + (48u << 20));
    bf16_t* Kb   = (bf16_t*)(ws + (64u << 20));
    bf16_t* Vt   = (bf16_t*)(ws + (80u << 20));
    bf16_t* ctx  = (bf16_t*)(ws + (96u << 20));

    cast_all<<<24576, 256, 0, stream>>>(x, Wq, Wk, Wv, Wo, xb, wqkv, wob);

    dim3 gq(6144 / 256, MM / 256);
    gemm_qkv<<<gq, 512, 0, stream>>>(xb, wqkv, Qb, Kb, Vt, pos);

    attn_kernel<<<512, 256, 0, stream>>>(Qb, Kb, Vt, ctx);

    dim3 gg(2048 / 128, MM / 128);
    gemm_out<<<gg, 256, 0, stream>>>(ctx, wob, (float*)d_out);
}

// Round 10
// 399.364 us; speedup vs baseline: 1.0724x; 1.0367x over previous
//
#include <hip/hip_runtime.h>
#include <cstdint>
#include <cstddef>

typedef __bf16 bf16_t;
typedef __bf16 bf16x8 __attribute__((ext_vector_type(8)));
typedef float  f32x4  __attribute__((ext_vector_type(4)));

#define SEQ 2048
#define NH  16
#define HD  128
#define MM  4096   // b*s rows
#define KK  2048

// async global->LDS, 16B per lane, LDS dest = wave-uniform base + lane*16
#define ASYNC16(g, l) __builtin_amdgcn_global_load_lds( \
    (const __attribute__((address_space(1))) void*)(g), \
    (__attribute__((address_space(3))) void*)(l), 16, 0, 0)

#define MFMA16(a, b, c) __builtin_amdgcn_mfma_f32_16x16x32_bf16((a), (b), (c), 0, 0, 0)

// ---------------------------------------------------------------- one cast kernel
__global__ __launch_bounds__(256) void cast_all(const float* __restrict__ x,
                                                const float* __restrict__ Wq,
                                                const float* __restrict__ Wk,
                                                const float* __restrict__ Wv,
                                                const float* __restrict__ Wo,
                                                bf16_t* __restrict__ xb,
                                                bf16_t* __restrict__ wqkv,
                                                bf16_t* __restrict__ wob) {
    int i = blockIdx.x * 256 + threadIdx.x;     // 0..6M-1 float4 groups
    const float* src;
    bf16_t* dst;
    int off;
    if (i < 2097152) { src = x; dst = xb; off = i; }
    else {
        int j = i - 2097152;
        int sel = j >> 20; off = j & 0xFFFFF;
        if (sel < 3) { src = (sel == 0) ? Wq : (sel == 1) ? Wk : Wv; dst = wqkv + (size_t)sel * 4194304; }
        else         { src = Wo; dst = wob; }
    }
    float4 v = ((const float4*)src)[off];
    union { bf16_t h[4]; uint2 u; } t;
    t.h[0] = (bf16_t)v.x; t.h[1] = (bf16_t)v.y;
    t.h[2] = (bf16_t)v.z; t.h[3] = (bf16_t)v.w;
    ((uint2*)dst)[off] = t.u;
}

// ================================================================ 256x256 QKV GEMM, 4-phase/K-tile
// (R7 harness-verified body — best of three schedule variants: 147.5 us, 700 TF)
union SMemQ8 {
    bf16_t st[2][32768];     // 128 KB: [buf][ A: frag(mi,ks)*512 | B at +16384 ]
    bf16_t epi[64 * 264];    // epilogue transpose
};

__global__ __launch_bounds__(512, 2) void gemm_qkv(const bf16_t* __restrict__ A,
                                                   const bf16_t* __restrict__ B,
                                                   bf16_t* __restrict__ Qout,
                                                   bf16_t* __restrict__ Kout,
                                                   bf16_t* __restrict__ Vout,
                                                   const int* __restrict__ pos) {
    __shared__ SMemQ8 sm;
    const int tid = threadIdx.x;
    const int w = tid >> 6, l = tid & 63;       // 8 waves
    const int lane16 = l & 15, quad = l >> 4;
    const int tm = blockIdx.y, tn = blockIdx.x; // 256-row / 256-col tiles
    const int wm = w >> 2, wn = w & 3;          // 2M x 4N wave grid

    const int miA0 = wm * 8 + wn;
    const int miA1 = miA0 + 4;
    const int niB0 = (w >> 1) * 4 + (w & 1);
    const int niB1 = niB0 + 2;

    const bf16_t* gA0 = A + (size_t)(tm * 256 + miA0 * 16 + lane16) * KK + quad * 8;
    const bf16_t* gA1 = A + (size_t)(tm * 256 + miA1 * 16 + lane16) * KK + quad * 8;
    const bf16_t* gB0 = B + (size_t)(tn * 256 + niB0 * 16 + lane16) * KK + quad * 8;
    const bf16_t* gB1 = B + (size_t)(tn * 256 + niB1 * 16 + lane16) * KK + quad * 8;

    const int dA0 = miA0 * 1024;
    const int dA1 = miA1 * 1024;
    const int dB0 = 16384 + niB0 * 1024;
    const int dB1 = 16384 + niB1 * 1024;

    f32x4 acc[8][4];
    #pragma unroll
    for (int i = 0; i < 8; i++)
        #pragma unroll
        for (int j = 0; j < 4; j++) acc[i][j] = (f32x4){0.f, 0.f, 0.f, 0.f};

    ASYNC16(gA0,      &sm.st[0][dA0]);
    ASYNC16(gA0 + 32, &sm.st[0][dA0 + 512]);
    ASYNC16(gB0,      &sm.st[0][dB0]);
    ASYNC16(gB0 + 32, &sm.st[0][dB0 + 512]);
    ASYNC16(gB1,      &sm.st[0][dB1]);
    ASYNC16(gB1 + 32, &sm.st[0][dB1 + 512]);
    ASYNC16(gA1,      &sm.st[0][dA1]);
    ASYNC16(gA1 + 32, &sm.st[0][dA1 + 512]);
    gA0 += 64; gA1 += 64; gB0 += 64; gB1 += 64;

    const int NT = KK / 64;                     // 32 K-tiles
    for (int t = 0; t < NT; ++t) {
        const int buf = t & 1, nbuf = buf ^ 1;
        const bool pf = (t + 1 < NT);
        const bf16_t* sa = &sm.st[buf][0];
        const bf16_t* sb = &sm.st[buf][16384];
        bf16_t* nb = &sm.st[nbuf][0];

        // ---- phase 1
        asm volatile("s_waitcnt vmcnt(4) lgkmcnt(0)" ::: "memory");
        __builtin_amdgcn_s_barrier();
        asm volatile("" ::: "memory");
        if (pf) { ASYNC16(gA0, nb + dA0); ASYNC16(gA0 + 32, nb + dA0 + 512); }
        bf16x8 a0[4][2], b0[2][2];
        #pragma unroll
        for (int i = 0; i < 4; i++)
            #pragma unroll
            for (int ks = 0; ks < 2; ks++)
                a0[i][ks] = *(const bf16x8*)(sa + ((wm * 8 + i) * 2 + ks) * 512 + l * 8);
        #pragma unroll
        for (int j = 0; j < 2; j++)
            #pragma unroll
            for (int ks = 0; ks < 2; ks++)
                b0[j][ks] = *(const bf16x8*)(sb + ((wn * 4 + j) * 2 + ks) * 512 + l * 8);
        __builtin_amdgcn_s_setprio(1);
        #pragma unroll
        for (int i = 0; i < 4; i++)
            #pragma unroll
            for (int j = 0; j < 2; j++) {
                acc[i][j] = MFMA16(a0[i][0], b0[j][0], acc[i][j]);
                acc[i][j] = MFMA16(a0[i][1], b0[j][1], acc[i][j]);
            }
        __builtin_amdgcn_s_setprio(0);

        // ---- phase 2
        if (pf) { asm volatile("s_waitcnt vmcnt(4)" ::: "memory"); }
        else    { asm volatile("s_waitcnt vmcnt(2)" ::: "memory"); }
        __builtin_amdgcn_s_barrier();
        asm volatile("" ::: "memory");
        if (pf) { ASYNC16(gB0, nb + dB0); ASYNC16(gB0 + 32, nb + dB0 + 512); }
        bf16x8 b1[2][2];
        #pragma unroll
        for (int j = 0; j < 2; j++)
            #pragma unroll
            for (int ks = 0; ks < 2; ks++)
                b1[j][ks] = *(const bf16x8*)(sb + ((wn * 4 + 2 + j) * 2 + ks) * 512 + l * 8);
        __builtin_amdgcn_s_setprio(1);
        #pragma unroll
        for (int i = 0; i < 4; i++)
            #pragma unroll
            for (int j = 0; j < 2; j++) {
                acc[i][2 + j] = MFMA16(a0[i][0], b1[j][0], acc[i][2 + j]);
                acc[i][2 + j] = MFMA16(a0[i][1], b1[j][1], acc[i][2 + j]);
            }
        __builtin_amdgcn_s_setprio(0);

        // ---- phase 3
        if (pf) { asm volatile("s_waitcnt vmcnt(4)" ::: "memory"); }
        else    { asm volatile("s_waitcnt vmcnt(0)" ::: "memory"); }
        __builtin_amdgcn_s_barrier();
        asm volatile("" ::: "memory");
        if (pf) { ASYNC16(gB1, nb + dB1); ASYNC16(gB1 + 32, nb + dB1 + 512); }
        bf16x8 a1[4][2];
        #pragma unroll
        for (int i = 0; i < 4; i++)
            #pragma unroll
            for (int ks = 0; ks < 2; ks++)
                a1[i][ks] = *(const bf16x8*)(sa + ((wm * 8 + 4 + i) * 2 + ks) * 512 + l * 8);
        __builtin_amdgcn_s_setprio(1);
        #pragma unroll
        for (int i = 0; i < 4; i++)
            #pragma unroll
            for (int j = 0; j < 2; j++) {
                acc[4 + i][j] = MFMA16(a1[i][0], b0[j][0], acc[4 + i][j]);
                acc[4 + i][j] = MFMA16(a1[i][1], b0[j][1], acc[4 + i][j]);
            }
        __builtin_amdgcn_s_setprio(0);

        // ---- phase 4
        if (pf) {
            ASYNC16(gA1, nb + dA1); ASYNC16(gA1 + 32, nb + dA1 + 512);
            gA0 += 64; gA1 += 64; gB0 += 64; gB1 += 64;
        }
        __builtin_amdgcn_s_setprio(1);
        #pragma unroll
        for (int i = 0; i < 4; i++)
            #pragma unroll
            for (int j = 0; j < 2; j++) {
                acc[4 + i][2 + j] = MFMA16(a1[i][0], b1[j][0], acc[4 + i][2 + j]);
                acc[4 + i][2 + j] = MFMA16(a1[i][1], b1[j][1], acc[4 + i][2 + j]);
            }
        __builtin_amdgcn_s_setprio(0);
    }

    // ------------- epilogue (QKV + fused RoPE) -------------
    const int mbase = tm * 256;
    const int nb2   = tn * 256;
    const int sel   = nb2 >> 11;                // 0=Q 1=K 2=V
    const int hh0   = (nb2 & 2047) >> 7;
    const int bidx  = mbase >> 11;
    const int g   = tid >> 5;
    const int c8  = (tid & 31) * 8;

    if (sel < 2) {
        bf16_t* base = ((sel == 0) ? Qout : Kout) + (size_t)(bidx * NH) * SEQ * HD;
        const float qs = (sel == 0) ? 0.08838834764831845f : 1.0f;  // 1/sqrt(128) on Q
        for (int slice = 0; slice < 4; slice++) {
            __syncthreads();
            if (wm == (slice >> 1)) {
                for (int i2 = 0; i2 < 4; i2++) {
                    const int i = (slice & 1) * 4 + i2;
                    for (int j = 0; j < 4; j++)
                        for (int r = 0; r < 4; r++)
                            sm.epi[(i2 * 16 + quad * 4 + r) * 264 + wn * 64 + j * 16 + lane16] =
                                (bf16_t)acc[i][j][r];
                }
            }
            __syncthreads();
            const int head = hh0 + (c8 >> 7);
            const int d0   = c8 & 127;
            for (int p = 0; p < 4; p++) {
                const int rid = p * 16 + g;
                const int s = (mbase & 2047) + slice * 64 + rid;
                bf16x8 v = *(const bf16x8*)&sm.epi[rid * 264 + c8];
                const float pp = (float)pos[bidx * SEQ + s];
                union { bf16_t h8[8]; uint4 u; } o;
                for (int t = 0; t < 4; t++) {
                    const int fi = (d0 >> 1) + t;
                    const float freq = exp2f(-(float)fi * 0.20762050593045857f);
                    const float ang = pp * freq;
                    const float sn = __sinf(ang), cs = __cosf(ang);
                    const float x1 = (float)v[2 * t], x2 = (float)v[2 * t + 1];
                    o.h8[2 * t]     = (bf16_t)((x1 * cs - x2 * sn) * qs);
                    o.h8[2 * t + 1] = (bf16_t)((x1 * sn + x2 * cs) * qs);
                }
                *(uint4*)(base + (size_t)(head * SEQ + s) * HD + d0) = o.u;
            }
        }
    } else {
        const int s0 = mbase & 2047;
        for (int half = 0; half < 4; half++) {
            __syncthreads();
            if (wn == half) {
                for (int i = 0; i < 8; i++)
                    for (int j = 0; j < 4; j++) {
                        union { bf16_t h4[4]; uint2 u; } pk;
                        for (int r = 0; r < 4; r++) pk.h4[r] = (bf16_t)acc[i][j][r];
                        *(uint2*)&sm.epi[(j * 16 + lane16) * 264 + wm * 128 + i * 16 + quad * 4] = pk.u;
                    }
            }
            __syncthreads();
            const int head = hh0 + (half >> 1);
            bf16_t* dstb = Vout + (size_t)(bidx * NH + head) * HD * SEQ;
            for (int p = 0; p < 4; p++) {
                const int rid = p * 16 + g;
                const int dh  = (half & 1) * 64 + rid;
                bf16x8 v = *(const bf16x8*)&sm.epi[rid * 264 + c8];
                *(uint4*)(dstb + (size_t)dh * SEQ + s0 + c8) = *(const uint4*)&v;
            }
        }
    }
}

// ================================================================ 256x128 GEMM (gemm_out)
// R5 harness-verified body (256x128, 8 waves 4Mx2N, 3-buffer rotation, counted
// vmcnt(3), cluster-interleaved staging) with a direct fp32 store epilogue.
// Grid (16,16)=256 blocks, 72KB LDS + 64-reg acc -> 2 blocks/CU.
union SMemG {
    bf16_t st[3][24 * 512];      // 72 KB: [buf][frag f*512 + lane*8]; f<16 A, f>=16 B
};

__global__ __launch_bounds__(512, 4) void gemm_out(const bf16_t* __restrict__ A,
                                                   const bf16_t* __restrict__ B,
                                                   float* __restrict__ Cout) {
    __shared__ SMemG sm;
    const int tid = threadIdx.x;
    const int w = tid >> 6, l = tid & 63;       // 8 waves
    const int lane16 = l & 15, quad = l >> 4;
    const int tm = blockIdx.y, tn = blockIdx.x; // 256-row / 128-col tiles
    const int wm = w >> 1, wn = w & 1;          // 4M x 2N wave grid

    const int f0 = 3 * w, f1 = 3 * w + 1, f2 = 3 * w + 2;
    const bf16_t* p0 = (f0 < 16)
        ? A + (size_t)(tm * 256 + f0 * 16 + lane16) * KK + quad * 8
        : B + (size_t)(tn * 128 + (f0 - 16) * 16 + lane16) * KK + quad * 8;
    const bf16_t* p1 = (f1 < 16)
        ? A + (size_t)(tm * 256 + f1 * 16 + lane16) * KK + quad * 8
        : B + (size_t)(tn * 128 + (f1 - 16) * 16 + lane16) * KK + quad * 8;
    const bf16_t* p2 = (f2 < 16)
        ? A + (size_t)(tm * 256 + f2 * 16 + lane16) * KK + quad * 8
        : B + (size_t)(tn * 128 + (f2 - 16) * 16 + lane16) * KK + quad * 8;

    f32x4 acc[4][4];
    for (int i = 0; i < 4; i++)
        for (int j = 0; j < 4; j++) acc[i][j] = (f32x4){0.f, 0.f, 0.f, 0.f};

    ASYNC16(p0,      &sm.st[0][f0 * 512]);
    ASYNC16(p1,      &sm.st[0][f1 * 512]);
    ASYNC16(p2,      &sm.st[0][f2 * 512]);
    ASYNC16(p0 + 32, &sm.st[1][f0 * 512]);
    ASYNC16(p1 + 32, &sm.st[1][f1 * 512]);
    ASYNC16(p2 + 32, &sm.st[1][f2 * 512]);
    p0 += 64; p1 += 64; p2 += 64;

    const int NT = KK / 32;                     // 64 K-tiles
    int rdbuf = 0, stbuf = 2;
    for (int t = 0; t < NT; ++t) {
        if (t == NT - 1) { asm volatile("s_waitcnt vmcnt(0) lgkmcnt(0)" ::: "memory"); }
        else             { asm volatile("s_waitcnt vmcnt(3) lgkmcnt(0)" ::: "memory"); }
        __builtin_amdgcn_s_barrier();
        asm volatile("" ::: "memory");

        const bf16_t* rA = &sm.st[rdbuf][(wm * 4 + 0) * 512 + l * 8];
        const bf16_t* rB = &sm.st[rdbuf][(16 + wn * 4) * 512 + l * 8];
        const bool pf = (t + 2 < NT);
        bf16_t* sb = &sm.st[stbuf][0];

        // ---- cluster 1
        bf16x8 af0 = *(const bf16x8*)(rA + 0 * 512);
        bf16x8 af1 = *(const bf16x8*)(rA + 1 * 512);
        bf16x8 bf0 = *(const bf16x8*)(rB + 0 * 512);
        bf16x8 bf1 = *(const bf16x8*)(rB + 1 * 512);
        if (pf) ASYNC16(p0, sb + f0 * 512);
        __builtin_amdgcn_s_setprio(1);
        acc[0][0] = MFMA16(af0, bf0, acc[0][0]);
        acc[0][1] = MFMA16(af0, bf1, acc[0][1]);
        acc[1][0] = MFMA16(af1, bf0, acc[1][0]);
        acc[1][1] = MFMA16(af1, bf1, acc[1][1]);
        __builtin_amdgcn_s_setprio(0);

        // ---- cluster 2
        bf16x8 af2 = *(const bf16x8*)(rA + 2 * 512);
        bf16x8 af3 = *(const bf16x8*)(rA + 3 * 512);
        if (pf) ASYNC16(p1, sb + f1 * 512);
        __builtin_amdgcn_s_setprio(1);
        acc[2][0] = MFMA16(af2, bf0, acc[2][0]);
        acc[2][1] = MFMA16(af2, bf1, acc[2][1]);
        acc[3][0] = MFMA16(af3, bf0, acc[3][0]);
        acc[3][1] = MFMA16(af3, bf1, acc[3][1]);
        __builtin_amdgcn_s_setprio(0);

        // ---- cluster 3 + 4
        bf16x8 bf2 = *(const bf16x8*)(rB + 2 * 512);
        bf16x8 bf3 = *(const bf16x8*)(rB + 3 * 512);
        if (pf) ASYNC16(p2, sb + f2 * 512);
        __builtin_amdgcn_s_setprio(1);
        acc[0][2] = MFMA16(af0, bf2, acc[0][2]);
        acc[0][3] = MFMA16(af0, bf3, acc[0][3]);
        acc[1][2] = MFMA16(af1, bf2, acc[1][2]);
        acc[1][3] = MFMA16(af1, bf3, acc[1][3]);
        acc[2][2] = MFMA16(af2, bf2, acc[2][2]);
        acc[2][3] = MFMA16(af2, bf3, acc[2][3]);
        acc[3][2] = MFMA16(af3, bf2, acc[3][2]);
        acc[3][3] = MFMA16(af3, bf3, acc[3][3]);
        __builtin_amdgcn_s_setprio(0);

        if (pf) { p0 += 32; p1 += 32; p2 += 32; }
        rdbuf = (rdbuf == 2) ? 0 : rdbuf + 1;
        stbuf = (stbuf == 2) ? 0 : stbuf + 1;
    }

    // direct fp32 row-major stores: 16 lanes x 4B = 64B full lines
    const int mbase = tm * 256 + wm * 64;
    const int nbase = tn * 128 + wn * 64;
    for (int i = 0; i < 4; i++)
        for (int j = 0; j < 4; j++) {
            const int n  = nbase + j * 16 + lane16;
            const int m0 = mbase + i * 16 + quad * 4;
            for (int r = 0; r < 4; r++)
                Cout[(size_t)(m0 + r) * 2048 + n] = acc[i][j][r];
        }
}

// ---------------------------------------------------------------- causal flash attention
// (harness-verified version: two independent q-tile passes, __expf softmax,
//  T13 defer-max @8, tree row-max, T5 setprio)
__global__ __launch_bounds__(256) void attn_kernel(const bf16_t* __restrict__ Q,
                                                   const bf16_t* __restrict__ K,
                                                   const bf16_t* __restrict__ Vt,
                                                   bf16_t* __restrict__ ctx) {
    const int flat = blockIdx.x;
    const int bh = flat & 31;
    const int bt = flat >> 5;                   // 0..15
    const int h = bh & 15, b = bh >> 4;
    const bf16_t* Qh = Q  + (size_t)bh * SEQ * HD;
    const bf16_t* Kh = K  + (size_t)bh * SEQ * HD;
    const bf16_t* Vh = Vt + (size_t)bh * HD * SEQ;

    const int tid = threadIdx.x;
    const int w = tid >> 6, l = tid & 63;
    const int lane16 = l & 15, quad = l >> 4;

    __shared__ bf16_t kt[2][16 * 512];
    __shared__ bf16_t vt[2][16 * 512];
    __shared__ bf16_t pbuf[4][1024];

    for (int half = 0; half < 2; half++) {
        const int qt = half ? (31 - bt) : bt;   // q-tile of 64 rows
        const int q0 = qt * 64 + w * 16;

        bf16x8 qf[4];
        {
            const bf16_t* qrow = Qh + (size_t)(q0 + lane16) * HD + quad * 8;
            for (int kc = 0; kc < 4; kc++) qf[kc] = *(const bf16x8*)(qrow + kc * 32);
        }

        f32x4 o[8];
        for (int dt = 0; dt < 8; dt++) o[dt] = (f32x4){0.f, 0.f, 0.f, 0.f};
        float m_s = -INFINITY, l_s = 0.f;       // per-lane: row q = q0 + lane16

        __syncthreads();
        for (int ii = 0; ii < 4; ii++) {
            const int f = w * 4 + ii;
            const int nt = f >> 2, kc = f & 3;
            ASYNC16(Kh + (size_t)(nt * 16 + lane16) * HD + kc * 32 + quad * 8, &kt[0][f * 512]);
            const int dt = f >> 1, kk = f & 1;
            ASYNC16(Vh + (size_t)(dt * 16 + lane16) * SEQ + kk * 32 + quad * 8, &vt[0][f * 512]);
        }

        int cur = 0;
        for (int kb = 0; kb <= qt; kb++) {
            const int k0 = kb * 64;
            __syncthreads();
            if (kb < qt) {
                const int kn = k0 + 64;
                for (int ii = 0; ii < 4; ii++) {
                    const int f = w * 4 + ii;
                    const int nt = f >> 2, kc = f & 3;
                    ASYNC16(Kh + (size_t)(kn + nt * 16 + lane16) * HD + kc * 32 + quad * 8,
                            &kt[1 - cur][f * 512]);
                    const int dt = f >> 1, kk = f & 1;
                    ASYNC16(Vh + (size_t)(dt * 16 + lane16) * SEQ + kn + kk * 32 + quad * 8,
                            &vt[1 - cur][f * 512]);
                }
            }
            const bf16_t* ktc = kt[cur];
            const bf16_t* vtc = vt[cur];

            f32x4 sacc[4];
            for (int nt = 0; nt < 4; nt++) sacc[nt] = (f32x4){0.f, 0.f, 0.f, 0.f};
            __builtin_amdgcn_s_setprio(1);      // T5: favor this wave while MFMA cluster issues
            for (int nt = 0; nt < 4; nt++)
                for (int kc = 0; kc < 4; kc++) {
                    bf16x8 kf = *(const bf16x8*)&ktc[(nt * 4 + kc) * 512 + l * 8];
                    sacc[nt] = MFMA16(kf, qf[kc], sacc[nt]);
                }
            __builtin_amdgcn_s_setprio(0);
            if (kb == qt) {
                const int qg = q0 + lane16;
                for (int nt = 0; nt < 4; nt++)
                    for (int r = 0; r < 4; r++) {
                        const int kg = k0 + nt * 16 + quad * 4 + r;
                        if (kg > qg) sacc[nt][r] = -INFINITY;
                    }
            }
            // row-max reduce as a tree (depth 4+2; exposes v_max3 fusion — T17)
            float rmnt[4];
            for (int nt = 0; nt < 4; nt++)
                rmnt[nt] = fmaxf(fmaxf(sacc[nt][0], sacc[nt][1]),
                                 fmaxf(sacc[nt][2], sacc[nt][3]));
            float rowmax = fmaxf(fmaxf(rmnt[0], rmnt[1]), fmaxf(rmnt[2], rmnt[3]));
            rowmax = fmaxf(rowmax, __shfl_xor(rowmax, 16, 64));
            rowmax = fmaxf(rowmax, __shfl_xor(rowmax, 32, 64));

            // T13 defer-max: skip the O-rescale when no row grew by >8 ln-units
            float a = 1.f;
            const bool noresc = __all(rowmax <= m_s + 8.f) != 0;
            if (!noresc) {
                const float mnew = fmaxf(m_s, rowmax);
                a = __expf(m_s - mnew);         // first iter: exp(-inf)=0
                m_s = mnew;
            }
            float ssum = 0.f;
            for (int nt = 0; nt < 4; nt++) {
                union { bf16_t h4[4]; uint2 u; } pk;
                for (int r = 0; r < 4; r++) {
                    const float e = __expf(sacc[nt][r] - m_s);
                    ssum += e;
                    pk.h4[r] = (bf16_t)e;
                }
                const int addr = (nt >> 1) * 512 +
                                 (((nt & 1) * 2 + (quad >> 1)) * 16 + lane16) * 8 +
                                 (quad & 1) * 4;
                *(uint2*)&pbuf[w][addr] = pk.u;
            }
            ssum += __shfl_xor(ssum, 16, 64);
            ssum += __shfl_xor(ssum, 32, 64);
            l_s = l_s * a + ssum;

            if (!noresc) {
                float ar[4];
                for (int r = 0; r < 4; r++) ar[r] = __shfl(a, (quad << 2) | r, 16);
                for (int dt = 0; dt < 8; dt++)
                    for (int r = 0; r < 4; r++) o[dt][r] *= ar[r];
            }
            __builtin_amdgcn_s_setprio(1);      // T5: PV MFMA cluster
            for (int kk = 0; kk < 2; kk++) {
                bf16x8 pf = *(const bf16x8*)&pbuf[w][kk * 512 + l * 8];
                for (int dt = 0; dt < 8; dt++) {
                    bf16x8 vf = *(const bf16x8*)&vtc[(dt * 2 + kk) * 512 + l * 8];
                    o[dt] = MFMA16(pf, vf, o[dt]);
                }
            }
            __builtin_amdgcn_s_setprio(0);
            cur ^= 1;
        }

        float inv[4];
        for (int r = 0; r < 4; r++) inv[r] = 1.0f / __shfl(l_s, (quad << 2) | r, 16);
        for (int r = 0; r < 4; r++) {
            const int qg = q0 + quad * 4 + r;
            bf16_t* dst = ctx + ((size_t)(b * SEQ + qg)) * (NH * HD) + h * HD;
            for (int dt = 0; dt < 8; dt++)
                dst[dt * 16 + lane16] = (bf16_t)(o[dt][r] * inv[r]);
        }
        __syncthreads();
    }
}

// ---------------------------------------------------------------- launch
extern "C" void kernel_launch(void* const* d_in, const int* in_sizes, int n_in,
                              void* d_out, int out_size, void* d_ws, size_t ws_size,
                              hipStream_t stream) {
    const float* x  = (const float*)d_in[0];
    const int* pos  = (const int*)d_in[1];
    const float* Wq = (const float*)d_in[2];
    const float* Wk = (const float*)d_in[3];
    const float* Wv = (const float*)d_in[4];
    const float* Wo = (const float*)d_in[5];

    char* ws = (char*)d_ws;
    bf16_t* xb   = (bf16_t*)(ws);
    bf16_t* wqkv = (bf16_t*)(ws + (16u << 20));   // [6144,2048]
    bf16_t* wob  = (bf16_t*)(ws + (40u << 20));
    bf16_t* Qb   = (bf16_t*)(ws + (48u << 20));
    bf16_t* Kb   = (bf16_t*)(ws + (64u << 20));
    bf16_t* Vt   = (bf16_t*)(ws + (80u << 20));
    bf16_t* ctx  = (bf16_t*)(ws + (96u << 20));

    cast_all<<<24576, 256, 0, stream>>>(x, Wq, Wk, Wv, Wo, xb, wqkv, wob);

    dim3 gq(6144 / 256, MM / 256);
    gemm_qkv<<<gq, 512, 0, stream>>>(xb, wqkv, Qb, Kb, Vt, pos);

    attn_kernel<<<512, 256, 0, stream>>>(Qb, Kb, Vt, ctx);

    dim3 gg(2048 / 128, MM / 256);
    gemm_out<<<gg, 512, 0, stream>>>(ctx, wob, (float*)d_out);
}